// Round 1
// baseline (1279.434 us; speedup 1.0000x reference)
//
#include <hip/hip_runtime.h>

#define S_LEN 1024
#define D_DIM 64
#define QB 32
#define NTHREADS 512
#define LH_STRIDE 1032   // bf16 elems per logits row (1024 + 8 pad)
#define VT_STRIDE 68     // bf16 per Vt row (64 + 4 pad) -> 136 B, b64-aligned

#define LH_OFF 0
#define LL_OFF 66048
#define VTH_OFF 132096
#define VTL_OFF 140800
#define RSUM_OFF 149504
#define LDS_BYTES 149632

typedef short s16x8 __attribute__((ext_vector_type(8)));
typedef short s16x4 __attribute__((ext_vector_type(4)));
typedef float f32x4 __attribute__((ext_vector_type(4)));
typedef unsigned short u16;
typedef unsigned int u32;

static __device__ __forceinline__ float bf2f(u16 h) {
  return __builtin_bit_cast(float, ((u32)h) << 16);
}

static __device__ __forceinline__ u16 f2bf_rne(float f) {
  u32 u = __builtin_bit_cast(u32, f);
  return (u16)((u + 0x7fffu + ((u >> 16) & 1u)) >> 16);
}

// split fp32 into hi (truncated bf16) + lo (RNE bf16 of exact remainder);
// hi+lo represents f to ~2^-17 relative error.
static __device__ __forceinline__ void split2(float f, u16& h, u16& l) {
  u32 u = __builtin_bit_cast(u32, f);
  h = (u16)(u >> 16);
  float hf = __builtin_bit_cast(float, u & 0xffff0000u);
  l = f2bf_rne(f - hf);
}

static __device__ __forceinline__ f32x4 mfma16(s16x8 a, s16x8 b, f32x4 c) {
  return __builtin_amdgcn_mfma_f32_16x16x32_bf16(a, b, c, 0, 0, 0);
}

static __device__ __forceinline__ void cvt8(f32x4 a, f32x4 b, s16x8& h, s16x8& l) {
  s16x8 hh, ll;
#pragma unroll
  for (int j = 0; j < 8; ++j) {
    float fj = (j < 4) ? a[j] : b[j - 4];
    u16 hb, lb;
    split2(fj, hb, lb);
    hh[j] = (short)hb;
    ll[j] = (short)lb;
  }
  h = hh; l = ll;
}

extern "C" __global__ void __launch_bounds__(NTHREADS, 1)
attn_fused(const float* __restrict__ qg, const float* __restrict__ kg,
           const float* __restrict__ vg, const float* __restrict__ mg,
           float* __restrict__ og, float* __restrict__ wg)
{
  extern __shared__ char smem[];
  u16* Lh = (u16*)(smem + LH_OFF);
  u16* Ll = (u16*)(smem + LL_OFF);
  u16* Vth = (u16*)(smem + VTH_OFF);
  u16* Vtl = (u16*)(smem + VTL_OFF);
  float* rinv = (float*)(smem + RSUM_OFF);

  const int tid = threadIdx.x;
  const int wave = tid >> 6;
  const int lane = tid & 63;
  const int l15 = lane & 15;
  const int lg4 = lane >> 4;

  const int qb = blockIdx.x;   // 0..31
  const int bh = blockIdx.y;   // 0..127
  const int qbase = qb * QB;

  const float* qp = qg + (size_t)bh * S_LEN * D_DIM;
  const float* kp = kg + (size_t)bh * S_LEN * D_DIM;
  const float* vp = vg + (size_t)bh * S_LEN * D_DIM;

  // ---------------- Phase 1: logits = QK^T/8 + mask_padded * -1e9 ----------------
  // A-frag (Q): row = lane&15, k = (lane>>4)*8 + i ; B-frag (K^T): col = lane&15 (k-row),
  // contiguous d from K's row-major layout. hi/lo split for fp32 accuracy.
  s16x8 qh[2][2], ql[2][2];
#pragma unroll
  for (int rt = 0; rt < 2; ++rt) {
    const float* qrow = qp + (size_t)(qbase + rt * 16 + l15) * D_DIM + lg4 * 8;
#pragma unroll
    for (int ks = 0; ks < 2; ++ks) {
      f32x4 a = *(const f32x4*)(qrow + ks * 32);
      f32x4 b = *(const f32x4*)(qrow + ks * 32 + 4);
      cvt8(a, b, qh[rt][ks], ql[rt][ks]);
    }
  }

  const int colbase = wave * 128;   // each wave owns 128 columns, both row-tiles
#pragma unroll 1
  for (int ct = 0; ct < 8; ++ct) {
    const int cb = colbase + ct * 16;
    const int t = cb + l15;
    const float* krow = kp + (size_t)t * D_DIM + lg4 * 8;
    s16x8 kh[2], kl[2];
#pragma unroll
    for (int ks = 0; ks < 2; ++ks) {
      f32x4 a = *(const f32x4*)(krow + ks * 32);
      f32x4 b = *(const f32x4*)(krow + ks * 32 + 4);
      cvt8(a, b, kh[ks], kl[ks]);
    }
#pragma unroll
    for (int rt = 0; rt < 2; ++rt) {
      f32x4 acc = {0.f, 0.f, 0.f, 0.f};
#pragma unroll
      for (int ks = 0; ks < 2; ++ks) {
        acc = mfma16(qh[rt][ks], kh[ks], acc);
        acc = mfma16(qh[rt][ks], kl[ks], acc);
        acc = mfma16(ql[rt][ks], kh[ks], acc);
      }
#pragma unroll
      for (int j = 0; j < 4; ++j) {
        const int rl = rt * 16 + lg4 * 4 + j;      // local row (C/D: row=(lane>>4)*4+reg)
        const int s = qbase + rl;                  // global query index
        float mv = 0.f;
        if (s > 0 && t > 0) mv = mg[(size_t)(s - 1) * (S_LEN - 1) + (t - 1)];
        float lgt = fmaf(mv, -1.0e9f, acc[j] * 0.125f);
        u16 hb, lb;
        split2(lgt, hb, lb);
        Lh[rl * LH_STRIDE + t] = hb;
        Ll[rl * LH_STRIDE + t] = lb;
      }
    }
  }
  __syncthreads();

  // ---------------- Phase 2: row softmax; write normalized weights to global ----------------
  {
    const int row = tid >> 4;        // 0..31, one row per 16 lanes (in-wave)
    const int ic = (tid & 15) * 4;   // 4-col chunks, 16 chunks per thread
    float ev[64];
    float m = -3.402823466e38f;
#pragma unroll
    for (int g = 0; g < 16; ++g) {
      const int col = g * 64 + ic;
      s16x4 h4 = *(const s16x4*)&Lh[row * LH_STRIDE + col];
      s16x4 l4 = *(const s16x4*)&Ll[row * LH_STRIDE + col];
#pragma unroll
      for (int j = 0; j < 4; ++j) {
        float f = bf2f((u16)h4[j]) + bf2f((u16)l4[j]);
        ev[g * 4 + j] = f;
        m = fmaxf(m, f);
      }
    }
#pragma unroll
    for (int off = 1; off < 16; off <<= 1) m = fmaxf(m, __shfl_xor(m, off, 64));
    float sum = 0.f;
#pragma unroll
    for (int g = 0; g < 16; ++g) {
      const int col = g * 64 + ic;
      s16x4 h4, l4;
#pragma unroll
      for (int j = 0; j < 4; ++j) {
        float ex = __expf(ev[g * 4 + j] - m);
        ev[g * 4 + j] = ex;
        sum += ex;
        u16 hb, lb;
        split2(ex, hb, lb);
        h4[j] = (short)hb;
        l4[j] = (short)lb;
      }
      // in-place overwrite: same thread, same addresses -> no hazard
      *(s16x4*)&Lh[row * LH_STRIDE + col] = h4;
      *(s16x4*)&Ll[row * LH_STRIDE + col] = l4;
    }
#pragma unroll
    for (int off = 1; off < 16; off <<= 1) sum += __shfl_xor(sum, off, 64);
    const float inv = 1.0f / sum;
    if ((tid & 15) == 0) rinv[row] = inv;
    float* wrow = wg + (size_t)bh * S_LEN * S_LEN + (size_t)(qbase + row) * S_LEN;
#pragma unroll
    for (int g = 0; g < 16; ++g) {
      f32x4 wv;
#pragma unroll
      for (int j = 0; j < 4; ++j) wv[j] = ev[g * 4 + j] * inv;
      *(f32x4*)&wrow[g * 64 + ic] = wv;   // coalesced: 16 lanes x 16 B contiguous
    }
  }
  __syncthreads();

  // ---------------- Phase 3: out = (E · V) * inv ----------------
  const int rt = wave >> 2;
  const int ct = wave & 3;
  const int arow = rt * 16 + l15;       // E row for A-frag
  const int vrow = ct * 16 + l15;       // output d column == Vt row
  f32x4 acc = {0.f, 0.f, 0.f, 0.f};

#pragma unroll 1
  for (int tile = 0; tile < 16; ++tile) {
    __syncthreads();                    // previous tile's reads complete
    {
      // stage V[tile*64 .. +64) transposed as hi/lo bf16; wave w stages 8 t-rows
      const int tb = tile * 64 + wave * 8;
#pragma unroll
      for (int jj = 0; jj < 8; jj += 2) {
        float f0 = vp[(size_t)(tb + jj) * D_DIM + lane];       // coalesced 256 B
        float f1 = vp[(size_t)(tb + jj + 1) * D_DIM + lane];
        u16 h0, l0, h1, l1;
        split2(f0, h0, l0);
        split2(f1, h1, l1);
        const int tl = wave * 8 + jj;
        *(u32*)&Vth[lane * VT_STRIDE + tl] = (u32)h0 | ((u32)h1 << 16);
        *(u32*)&Vtl[lane * VT_STRIDE + tl] = (u32)l0 | ((u32)l1 << 16);
      }
    }
    __syncthreads();
#pragma unroll
    for (int kk = 0; kk < 2; ++kk) {
      const int t0 = tile * 64 + kk * 32 + lg4 * 8;
      s16x8 ah = *(const s16x8*)&Lh[arow * LH_STRIDE + t0];   // 16B-aligned
      s16x8 al = *(const s16x8*)&Ll[arow * LH_STRIDE + t0];
      const int vo = vrow * VT_STRIDE + kk * 32 + lg4 * 8;    // 8B-aligned
      s16x4 b0 = *(const s16x4*)&Vth[vo];
      s16x4 b1 = *(const s16x4*)&Vth[vo + 4];
      s16x4 c0 = *(const s16x4*)&Vtl[vo];
      s16x4 c1 = *(const s16x4*)&Vtl[vo + 4];
      s16x8 bh = __builtin_shufflevector(b0, b1, 0, 1, 2, 3, 4, 5, 6, 7);
      s16x8 bl = __builtin_shufflevector(c0, c1, 0, 1, 2, 3, 4, 5, 6, 7);
      acc = mfma16(ah, bh, acc);   // Eh*Vh
      acc = mfma16(ah, bl, acc);   // Eh*Vl
      acc = mfma16(al, bh, acc);   // El*Vh   (El*Vl ~2^-18, dropped)
    }
  }

  float* op = og + (size_t)bh * S_LEN * D_DIM;
  const f32x4 iv = *(const f32x4*)&rinv[rt * 16 + lg4 * 4];
#pragma unroll
  for (int j = 0; j < 4; ++j) {
    const int rl = rt * 16 + lg4 * 4 + j;
    op[(size_t)(qbase + rl) * D_DIM + ct * 16 + l15] = acc[j] * iv[j];
  }
}

extern "C" void kernel_launch(void* const* d_in, const int* in_sizes, int n_in,
                              void* d_out, int out_size, void* d_ws, size_t ws_size,
                              hipStream_t stream) {
  const float* q = (const float*)d_in[0];
  const float* k = (const float*)d_in[1];
  const float* v = (const float*)d_in[2];
  const float* m = (const float*)d_in[3];
  float* out = (float*)d_out;
  float* w = out + (size_t)8 * 16 * S_LEN * D_DIM;   // weights follow output (tuple order)

  hipFuncSetAttribute((const void*)attn_fused,
                      hipFuncAttributeMaxDynamicSharedMemorySize, LDS_BYTES);
  dim3 grid(S_LEN / QB, 8 * 16);
  attn_fused<<<grid, NTHREADS, LDS_BYTES, stream>>>(q, k, v, m, out, w);
}

// Round 2
// 1259.731 us; speedup vs baseline: 1.0156x; 1.0156x over previous
//
#include <hip/hip_runtime.h>

#define S_LEN 1024
#define D_DIM 64
#define QB 32
#define NTHREADS 1024
#define LH_STRIDE 1032   // u16 per logits row (1024 + 8 pad), 2064 B (16B-mult)
#define VTS 40           // u16 per Vt row (32 t + 8 pad) -> 80 B (16B-mult)
#define VBUF_U16 (64 * VTS)   // 2560 u16 = 5120 B per buffer

#define LH_OFF 0
#define LL_OFF 66048
#define VTH_OFF 132096             // 2 bufs x 5120 B
#define VTL_OFF (132096 + 10240)   // 142336, 2 bufs x 5120 B
#define RINV_OFF 152576
#define LDS_BYTES 152704           // <= 160 KiB

typedef short s16x8 __attribute__((ext_vector_type(8)));
typedef short s16x4 __attribute__((ext_vector_type(4)));
typedef float f32x4 __attribute__((ext_vector_type(4)));
typedef unsigned short u16;
typedef unsigned int u32;

static __device__ __forceinline__ float bf2f(u16 h) {
  return __builtin_bit_cast(float, ((u32)h) << 16);
}

static __device__ __forceinline__ u16 f2bf_rne(float f) {
  u32 u = __builtin_bit_cast(u32, f);
  return (u16)((u + 0x7fffu + ((u >> 16) & 1u)) >> 16);
}

// fp32 -> bf16 hi (trunc) + bf16 lo (RNE of remainder); hi+lo ~ 2^-17 rel err
static __device__ __forceinline__ void split2(float f, u16& h, u16& l) {
  u32 u = __builtin_bit_cast(u32, f);
  h = (u16)(u >> 16);
  float hf = __builtin_bit_cast(float, u & 0xffff0000u);
  l = f2bf_rne(f - hf);
}

static __device__ __forceinline__ f32x4 mfma16(s16x8 a, s16x8 b, f32x4 c) {
  return __builtin_amdgcn_mfma_f32_16x16x32_bf16(a, b, c, 0, 0, 0);
}

static __device__ __forceinline__ void cvt8(f32x4 a, f32x4 b, s16x8& h, s16x8& l) {
  s16x8 hh, ll;
#pragma unroll
  for (int j = 0; j < 8; ++j) {
    float fj = (j < 4) ? a[j] : b[j - 4];
    u16 hb, lb;
    split2(fj, hb, lb);
    hh[j] = (short)hb;
    ll[j] = (short)lb;
  }
  h = hh; l = ll;
}

extern "C" __global__ void __launch_bounds__(NTHREADS, 4)
attn_fused(const float* __restrict__ qg, const float* __restrict__ kg,
           const float* __restrict__ vg, const float* __restrict__ mg,
           float* __restrict__ og, float* __restrict__ wg)
{
  extern __shared__ char smem[];
  u16* Lh = (u16*)(smem + LH_OFF);
  u16* Ll = (u16*)(smem + LL_OFF);
  u16* Vth = (u16*)(smem + VTH_OFF);
  u16* Vtl = (u16*)(smem + VTL_OFF);
  float* rinv = (float*)(smem + RINV_OFF);

  const int tid = threadIdx.x;
  const int wave = tid >> 6;       // 0..15
  const int lane = tid & 63;
  const int l15 = lane & 15;
  const int lg4 = lane >> 4;

  const int qb = blockIdx.x;   // 0..31
  const int bh = blockIdx.y;   // 0..127
  const int qbase = qb * QB;

  const float* qp = qg + (size_t)bh * S_LEN * D_DIM;
  const float* kp = kg + (size_t)bh * S_LEN * D_DIM;
  const float* vp = vg + (size_t)bh * S_LEN * D_DIM;

  // ============ Phase 1: logits = QK^T/8 + mask_padded * -1e9 -> LDS hi/lo ============
  // A-frag (Q): row=lane&15, k=(lane>>4)*8+i ; B-frag (K): col(t)=lane&15, same k.
  // C/D: col=lane&15(t), row=(lane>>4)*4+j. (verified correct in round 1)
  {
    s16x8 qh[2][2], ql[2][2];
#pragma unroll
    for (int rt = 0; rt < 2; ++rt) {
      const float* qrow = qp + (size_t)(qbase + rt * 16 + l15) * D_DIM + lg4 * 8;
#pragma unroll
      for (int ks = 0; ks < 2; ++ks) {
        f32x4 a = *(const f32x4*)(qrow + ks * 32);
        f32x4 b = *(const f32x4*)(qrow + ks * 32 + 4);
        cvt8(a, b, qh[rt][ks], ql[rt][ks]);
      }
    }

    const int colbase = wave * 64;   // each of 16 waves owns 64 columns
#pragma unroll 2
    for (int ct = 0; ct < 4; ++ct) {
      const int t = colbase + ct * 16 + l15;
      const float* krow = kp + (size_t)t * D_DIM + lg4 * 8;
      s16x8 kh[2], kl[2];
#pragma unroll
      for (int ks = 0; ks < 2; ++ks) {
        f32x4 a = *(const f32x4*)(krow + ks * 32);
        f32x4 b = *(const f32x4*)(krow + ks * 32 + 4);
        cvt8(a, b, kh[ks], kl[ks]);
      }
#pragma unroll
      for (int rt = 0; rt < 2; ++rt) {
        f32x4 acc = {0.f, 0.f, 0.f, 0.f};
#pragma unroll
        for (int ks = 0; ks < 2; ++ks) {
          acc = mfma16(qh[rt][ks], kh[ks], acc);
          acc = mfma16(qh[rt][ks], kl[ks], acc);
          acc = mfma16(ql[rt][ks], kh[ks], acc);
        }
#pragma unroll
        for (int j = 0; j < 4; ++j) {
          const int rl = rt * 16 + lg4 * 4 + j;
          const int s = qbase + rl;
          float mv = 0.f;
          if (s > 0 && t > 0) mv = mg[(size_t)(s - 1) * (S_LEN - 1) + (t - 1)];
          float lgt = fmaf(mv, -1.0e9f, acc[j] * 0.125f);
          u16 hb, lb;
          split2(lgt, hb, lb);
          Lh[rl * LH_STRIDE + t] = hb;
          Ll[rl * LH_STRIDE + t] = lb;
        }
      }
    }
  }
  __syncthreads();

  // ============ Phase 2: row softmax (multi-pass, no big register arrays) ============
  // 32 threads per row; thread owns cols (tid&31)*4 + g*128, g=0..7 (32 cols).
  const int row = tid >> 5;
  const int ci = (tid & 31) * 4;
  float inv;
  {
    const u16* lh = &Lh[row * LH_STRIDE];
    const u16* ll = &Ll[row * LH_STRIDE];
    float m = -3.402823466e38f;
#pragma unroll
    for (int g = 0; g < 8; ++g) {
      const int col = g * 128 + ci;
      s16x4 h4 = *(const s16x4*)&lh[col];
      s16x4 l4 = *(const s16x4*)&ll[col];
#pragma unroll
      for (int j = 0; j < 4; ++j)
        m = fmaxf(m, bf2f((u16)h4[j]) + bf2f((u16)l4[j]));
    }
#pragma unroll
    for (int off = 1; off < 32; off <<= 1) m = fmaxf(m, __shfl_xor(m, off, 64));

    float sum = 0.f;
#pragma unroll
    for (int g = 0; g < 8; ++g) {
      const int col = g * 128 + ci;
      s16x4 h4 = *(const s16x4*)&lh[col];
      s16x4 l4 = *(const s16x4*)&ll[col];
      s16x4 eh, el;
#pragma unroll
      for (int j = 0; j < 4; ++j) {
        float e = __expf(bf2f((u16)h4[j]) + bf2f((u16)l4[j]) - m);
        sum += e;
        u16 hb, lb;
        split2(e, hb, lb);
        eh[j] = (short)hb;
        el[j] = (short)lb;
      }
      // in-place (thread owns these cols exclusively)
      *(s16x4*)&Lh[row * LH_STRIDE + col] = eh;
      *(s16x4*)&Ll[row * LH_STRIDE + col] = el;
    }
#pragma unroll
    for (int off = 1; off < 32; off <<= 1) sum += __shfl_xor(sum, off, 64);
    inv = 1.0f / sum;
    if ((tid & 31) == 0) rinv[row] = inv;
  }
  __syncthreads();

  // ============ Phase 3: out = (E · V) * inv, V double-buffered, weights spread ============
  const int crt = (wave >> 2) & 1;   // waves 8..15 duplicate compute of 0..7
  const int cct = wave & 3;
  const int arow = crt * 16 + l15;
  const int vrow = cct * 16 + l15;
  float* wrow = wg + (size_t)bh * S_LEN * S_LEN + (size_t)(qbase + row) * S_LEN;
  f32x4 acc = {0.f, 0.f, 0.f, 0.f};

  // stage tile T rows r0=T*32+wave*2, r0+1 (2 rows per wave, 1 float per lane per row)
  float fA0, fA1, fB0 = 0.f, fB1 = 0.f;
  {
    const int r0 = wave * 2;
    float f0 = vp[(size_t)r0 * D_DIM + lane];
    float f1 = vp[(size_t)(r0 + 1) * D_DIM + lane];
    u16 h0, l0, h1, l1;
    split2(f0, h0, l0);
    split2(f1, h1, l1);
    const int idx = lane * VTS + wave * 2;
    *(u32*)&Vth[idx] = (u32)h0 | ((u32)h1 << 16);
    *(u32*)&Vtl[idx] = (u32)l0 | ((u32)l1 << 16);
    const int r1 = 32 + wave * 2;
    fA0 = vp[(size_t)r1 * D_DIM + lane];
    fA1 = vp[(size_t)(r1 + 1) * D_DIM + lane];
  }
  __syncthreads();

#pragma unroll 2
  for (int T = 0; T < 32; ++T) {
    const int cur = T & 1;
    // issue loads for tile T+2 (consumed at iter T+1's staging write)
    if (T + 2 < 32) {
      const int r0 = (T + 2) * 32 + wave * 2;
      fB0 = vp[(size_t)r0 * D_DIM + lane];
      fB1 = vp[(size_t)(r0 + 1) * D_DIM + lane];
    }
    // spread the 536-MB weights write across the loop: 1 f32x4/thread every 4 tiles
    if ((T & 3) == 0) {
      const int g = T >> 2;
      const int col = g * 128 + ci;
      s16x4 h4 = *(const s16x4*)&Lh[row * LH_STRIDE + col];
      s16x4 l4 = *(const s16x4*)&Ll[row * LH_STRIDE + col];
      f32x4 wv;
#pragma unroll
      for (int j = 0; j < 4; ++j)
        wv[j] = (bf2f((u16)h4[j]) + bf2f((u16)l4[j])) * inv;
      *(f32x4*)&wrow[col] = wv;
    }
    // MFMA on buf[cur]
    {
      const int t0 = T * 32 + lg4 * 8;
      s16x8 ah = *(const s16x8*)&Lh[arow * LH_STRIDE + t0];
      s16x8 al = *(const s16x8*)&Ll[arow * LH_STRIDE + t0];
      const int vo = cur * VBUF_U16 + vrow * VTS + lg4 * 8;
      s16x8 bh = *(const s16x8*)&Vth[vo];
      s16x8 bl = *(const s16x8*)&Vtl[vo];
      acc = mfma16(ah, bh, acc);
      acc = mfma16(ah, bl, acc);
      acc = mfma16(al, bh, acc);
    }
    // write tile T+1 into buf[cur^1] (its last readers passed the previous barrier)
    if (T + 1 < 32) {
      u16 h0, l0, h1, l1;
      split2(fA0, h0, l0);
      split2(fA1, h1, l1);
      const int idx = (cur ^ 1) * VBUF_U16 + lane * VTS + wave * 2;
      *(u32*)&Vth[idx] = (u32)h0 | ((u32)h1 << 16);
      *(u32*)&Vtl[idx] = (u32)l0 | ((u32)l1 << 16);
    }
    fA0 = fB0;
    fA1 = fB1;
    __syncthreads();
  }

  if (wave < 8) {
    float* op = og + (size_t)bh * S_LEN * D_DIM;
    const f32x4 iv = *(const f32x4*)&rinv[crt * 16 + lg4 * 4];
#pragma unroll
    for (int j = 0; j < 4; ++j) {
      const int rl = crt * 16 + lg4 * 4 + j;
      op[(size_t)(qbase + rl) * D_DIM + cct * 16 + l15] = acc[j] * iv[j];
    }
  }
}

extern "C" void kernel_launch(void* const* d_in, const int* in_sizes, int n_in,
                              void* d_out, int out_size, void* d_ws, size_t ws_size,
                              hipStream_t stream) {
  const float* q = (const float*)d_in[0];
  const float* k = (const float*)d_in[1];
  const float* v = (const float*)d_in[2];
  const float* m = (const float*)d_in[3];
  float* out = (float*)d_out;
  float* w = out + (size_t)8 * 16 * S_LEN * D_DIM;   // weights follow output (tuple order)

  hipFuncSetAttribute((const void*)attn_fused,
                      hipFuncAttributeMaxDynamicSharedMemorySize, LDS_BYTES);
  dim3 grid(S_LEN / QB, 8 * 16);
  attn_fused<<<grid, NTHREADS, LDS_BYTES, stream>>>(q, k, v, m, out, w);
}

// Round 3
// 1017.825 us; speedup vs baseline: 1.2570x; 1.2377x over previous
//
#include <hip/hip_runtime.h>

#define S_LEN 1024
#define D_DIM 64
#define QB 16
#define NTHREADS 1024
#define LSTR 1036      // f32 per logits row (1024 + 12 pad) = 4144 B, 16B-mult, bank-stride 12
#define ESTR 2072      // u16 per row (same 4144 B rows)
#define ELO 1024       // u16 col offset of E-lo half within a row
#define RINV_OFF 66304 // 16 * 4144
#define LDS_BYTES 66368

typedef short s16x8 __attribute__((ext_vector_type(8)));
typedef short s16x4 __attribute__((ext_vector_type(4)));
typedef float f32x4 __attribute__((ext_vector_type(4)));
typedef unsigned short u16;
typedef unsigned int u32;

static __device__ __forceinline__ u16 f2bf_rne(float f) {
  u32 u = __builtin_bit_cast(u32, f);
  return (u16)((u + 0x7fffu + ((u >> 16) & 1u)) >> 16);
}

// fp32 -> bf16 hi (trunc) + bf16 lo (RNE of remainder); hi+lo ~ 2^-17 rel err
static __device__ __forceinline__ void split2(float f, u16& h, u16& l) {
  u32 u = __builtin_bit_cast(u32, f);
  h = (u16)(u >> 16);
  float hf = __builtin_bit_cast(float, u & 0xffff0000u);
  l = f2bf_rne(f - hf);
}

static __device__ __forceinline__ f32x4 mfma16(s16x8 a, s16x8 b, f32x4 c) {
  return __builtin_amdgcn_mfma_f32_16x16x32_bf16(a, b, c, 0, 0, 0);
}

static __device__ __forceinline__ void cvt8(f32x4 a, f32x4 b, s16x8& h, s16x8& l) {
  s16x8 hh, ll;
#pragma unroll
  for (int j = 0; j < 8; ++j) {
    float fj = (j < 4) ? a[j] : b[j - 4];
    u16 hb, lb;
    split2(fj, hb, lb);
    hh[j] = (short)hb;
    ll[j] = (short)lb;
  }
  h = hh; l = ll;
}

extern "C" __global__ void __launch_bounds__(NTHREADS, 8)
attn_fused(const float* __restrict__ qg, const float* __restrict__ kg,
           const float* __restrict__ vg, const float* __restrict__ mg,
           float* __restrict__ og, float* __restrict__ wg)
{
  extern __shared__ char smem[];
  float* L = (float*)smem;            // [16][LSTR] f32 logits
  u16* E = (u16*)smem;                // same rows reused: E-hi cols 0..1023, E-lo at +ELO
  float* sc = (float*)smem;           // 16 KB scratch overlay (after barrier 3)
  float* rinv = (float*)(smem + RINV_OFF);

  const int tid = threadIdx.x;
  const int wave = tid >> 6;          // 0..15
  const int lane = tid & 63;
  const int l15 = lane & 15;
  const int lg4 = lane >> 4;

  // XCD-aware swizzle (8192 % 8 == 0 -> bijective): XCD x works bh in [16x,16x+16)
  const int bid = (int)blockIdx.x;
  const int swz = (bid & 7) * 1024 + (bid >> 3);
  const int qb = swz & 63;            // 0..63
  const int bh = swz >> 6;            // 0..127
  const int qbase = qb * QB;

  const float* qp = qg + (size_t)bh * S_LEN * D_DIM;
  const float* kp = kg + (size_t)bh * S_LEN * D_DIM;
  const float* vp = vg + (size_t)bh * S_LEN * D_DIM;

  // ===== Phase 1: L[s][t] = (q/8)ยทk + mask_padded * -1e9  (f32 in LDS) =====
  // A-frag: row=lane&15 (q), k=(lane>>4)*8+i ; B-frag: col=lane&15 (t), same k.
  // C/D: col=lane&15 (t), row=(lane>>4)*4+j (q).   [layout verified rounds 1-2]
  {
    s16x8 qh[2], ql[2];
    const float* qrow = qp + (size_t)(qbase + l15) * D_DIM + lg4 * 8;
#pragma unroll
    for (int ks = 0; ks < 2; ++ks) {
      f32x4 a = *(const f32x4*)(qrow + ks * 32);
      f32x4 b = *(const f32x4*)(qrow + ks * 32 + 4);
#pragma unroll
      for (int j = 0; j < 4; ++j) { a[j] *= 0.125f; b[j] *= 0.125f; }  // fold 1/sqrt(64)
      cvt8(a, b, qh[ks], ql[ks]);
    }

#pragma unroll 1
    for (int ct = 0; ct < 4; ++ct) {
      const int t = wave * 64 + ct * 16 + l15;     // 16 waves cover 1024 t
      const float* krow = kp + (size_t)t * D_DIM + lg4 * 8;
      s16x8 kh[2], kl[2];
#pragma unroll
      for (int ks = 0; ks < 2; ++ks) {
        f32x4 a = *(const f32x4*)(krow + ks * 32);
        f32x4 b = *(const f32x4*)(krow + ks * 32 + 4);
        cvt8(a, b, kh[ks], kl[ks]);
      }
      f32x4 acc = {0.f, 0.f, 0.f, 0.f};
#pragma unroll
      for (int ks = 0; ks < 2; ++ks) {
        acc = mfma16(qh[ks], kh[ks], acc);
        acc = mfma16(qh[ks], kl[ks], acc);
        acc = mfma16(ql[ks], kh[ks], acc);
      }
#pragma unroll
      for (int j = 0; j < 4; ++j) {
        const int rl = lg4 * 4 + j;
        const int s = qbase + rl;
        float mv = 0.f;
        if (s > 0 && t > 0) mv = mg[(size_t)(s - 1) * (S_LEN - 1) + (t - 1)];
        L[rl * LSTR + t] = fmaf(mv, -1.0e9f, acc[j]);
      }
    }
  }
  __syncthreads();

  // ===== Phase 2: one wave per row; softmax; weights -> global; E(hi/lo) in place =====
  {
    const float* Lr = L + wave * LSTR;
    float m = -3.402823466e38f;
#pragma unroll
    for (int g = 0; g < 4; ++g) {
      f32x4 lv = *(const f32x4*)&Lr[lane * 4 + g * 256];
#pragma unroll
      for (int j = 0; j < 4; ++j) m = fmaxf(m, lv[j]);
    }
#pragma unroll
    for (int off = 1; off < 64; off <<= 1) m = fmaxf(m, __shfl_xor(m, off, 64));

    f32x4 e[4];
    float sum = 0.f;
#pragma unroll
    for (int g = 0; g < 4; ++g) {
      f32x4 lv = *(const f32x4*)&Lr[lane * 4 + g * 256];
#pragma unroll
      for (int j = 0; j < 4; ++j) {
        float ex = __expf(lv[j] - m);
        e[g][j] = ex;
        sum += ex;
      }
    }
#pragma unroll
    for (int off = 1; off < 64; off <<= 1) sum += __shfl_xor(sum, off, 64);
    const float inv = 1.0f / sum;
    if (lane == 0) rinv[wave] = inv;

    float* wrow = wg + (size_t)bh * S_LEN * S_LEN + (size_t)(qbase + wave) * S_LEN;
    u16* Er = E + wave * ESTR;
#pragma unroll
    for (int g = 0; g < 4; ++g) {
      const int col = lane * 4 + g * 256;
      f32x4 wv;
      s16x4 eh, el;
#pragma unroll
      for (int j = 0; j < 4; ++j) {
        wv[j] = e[g][j] * inv;
        u16 hb, lb;
        split2(e[g][j], hb, lb);
        eh[j] = (short)hb;
        el[j] = (short)lb;
      }
      *(f32x4*)&wrow[col] = wv;            // coalesced 1 KB per wave per g
      *(s16x4*)&Er[col] = eh;              // in-row overlay (this wave owns the row)
      *(s16x4*)&Er[ELO + col] = el;
    }
  }
  __syncthreads();

  // ===== Phase 3: PV, barrier-free; V straight from global (L2), split-K over t =====
  const int g3 = wave >> 2;               // t-range group 0..3
  const int ct = wave & 3;                // d-tile 0..3
  const int dcol = ct * 16 + l15;
  f32x4 acc = {0.f, 0.f, 0.f, 0.f};
#pragma unroll 2
  for (int T = g3 * 8; T < g3 * 8 + 8; ++T) {
    const int t0 = T * 32 + lg4 * 8;
    s16x8 vh, vl;
#pragma unroll
    for (int i = 0; i < 8; ++i) {
      u16 hb, lb;
      split2(vp[(size_t)(t0 + i) * D_DIM + dcol], hb, lb);
      vh[i] = (short)hb;
      vl[i] = (short)lb;
    }
    s16x8 ah = *(const s16x8*)&E[l15 * ESTR + t0];
    s16x8 al = *(const s16x8*)&E[l15 * ESTR + ELO + t0];
    acc = mfma16(ah, vh, acc);
    acc = mfma16(ah, vl, acc);
    acc = mfma16(al, vh, acc);
  }
  __syncthreads();                        // all E reads done before scratch overlay

#pragma unroll
  for (int j = 0; j < 4; ++j)
    sc[g3 * 1024 + (lg4 * 4 + j) * 64 + dcol] = acc[j];
  __syncthreads();

  // reduce 4 split-K partials; scale by 1/sum; store output
  {
    const int q = wave;                   // 0..15
    const int d = lane;                   // 0..63
    float s = sc[q * 64 + d] + sc[1024 + q * 64 + d] +
              sc[2048 + q * 64 + d] + sc[3072 + q * 64 + d];
    og[(size_t)bh * S_LEN * D_DIM + (size_t)(qbase + q) * D_DIM + d] = s * rinv[q];
  }
}

extern "C" void kernel_launch(void* const* d_in, const int* in_sizes, int n_in,
                              void* d_out, int out_size, void* d_ws, size_t ws_size,
                              hipStream_t stream) {
  const float* q = (const float*)d_in[0];
  const float* k = (const float*)d_in[1];
  const float* v = (const float*)d_in[2];
  const float* m = (const float*)d_in[3];
  float* out = (float*)d_out;
  float* w = out + (size_t)8 * 16 * S_LEN * D_DIM;   // weights follow output (tuple order)

  hipFuncSetAttribute((const void*)attn_fused,
                      hipFuncAttributeMaxDynamicSharedMemorySize, LDS_BYTES);
  attn_fused<<<dim3(8192), NTHREADS, LDS_BYTES, stream>>>(q, k, v, m, out, w);
}